// Round 10
// baseline (751.133 us; speedup 1.0000x reference)
//
#include <hip/hip_runtime.h>
#include <hip/hip_bf16.h>
#include <cstdint>
#include <cstddef>

// ---------- types ----------
typedef __attribute__((ext_vector_type(8))) short short8;   // bf16 x8 (4 VGPRs)
typedef __attribute__((ext_vector_type(4))) short short4v;  // bf16 x4
typedef __attribute__((ext_vector_type(4))) float floatx4;

#define D_MODEL 512
#define HDIM    2048
#define TSEQ    16384
#define NTOK    65536   // B*T = 4*16384

// ---------- helpers ----------
__device__ __forceinline__ float bf2f(short s) {
  union { unsigned u; float f; } v; v.u = ((unsigned)(unsigned short)s) << 16; return v.f;
}
__device__ __forceinline__ short f2bf(float f) {
  union { float fv; unsigned u; } v; v.fv = f;
  unsigned u = v.u;
  u += 0x7FFFu + ((u >> 16) & 1u);   // RNE
  return (short)(u >> 16);
}
__device__ __forceinline__ void gload_lds16(const void* g, void* l) {
  // width=16 async global->LDS; LDS dest = wave-uniform base + lane*16 (m104)
  __builtin_amdgcn_global_load_lds((const __attribute__((address_space(1))) void*)g,
                                   (__attribute__((address_space(3))) void*)l, 16, 0, 0);
}

// ---------- weight convert + transpose: W[K][N] f32 -> Wt[N][K] bf16 ----------
__global__ void wt_transpose(const float* __restrict__ W, short* __restrict__ Wt,
                             const int K, const int N) {
  __shared__ float t[64][65];
  const int tid = threadIdx.x;
  const long k0 = (long)blockIdx.x * 64;
  const long n0 = (long)blockIdx.y * 64;
  const int rr = tid >> 4;
  const int cc = (tid & 15) * 4;
#pragma unroll
  for (int i = 0; i < 4; ++i) {
    const int r = rr + i * 16;
    const float4 v = *(const float4*)(W + (k0 + r) * N + n0 + cc);
    t[r][cc + 0] = v.x; t[r][cc + 1] = v.y; t[r][cc + 2] = v.z; t[r][cc + 3] = v.w;
  }
  __syncthreads();
#pragma unroll
  for (int i = 0; i < 4; ++i) {
    const int n = rr + i * 16;
    short4v o;
    o[0] = f2bf(t[cc + 0][n]);
    o[1] = f2bf(t[cc + 1][n]);
    o[2] = f2bf(t[cc + 2][n]);
    o[3] = f2bf(t[cc + 3][n]);
    *(short4v*)(Wt + (n0 + n) * K + k0 + cc) = o;
  }
}

// conv_w [512][17] f32 -> wT [17][512] f32
__global__ void convw_transpose(const float* __restrict__ cw, float* __restrict__ wT) {
  const int idx = blockIdx.x * 256 + threadIdx.x;
  if (idx >= 17 * D_MODEL) return;
  const int k = idx / D_MODEL;
  const int c = idx % D_MODEL;
  wT[idx] = cw[c * 17 + k];
}

// ---------- RMSNorm: one wave per row, f32 in -> bf16 out ----------
__global__ void rmsnorm_kernel(const float* __restrict__ x, const float* __restrict__ w,
                               short* __restrict__ outp) {
  const int lane = threadIdx.x & 63;
  const long row = (long)blockIdx.x * 4 + (threadIdx.x >> 6);
  const float* xr = x + row * D_MODEL + lane * 8;
  const float4 a = *(const float4*)xr;
  const float4 b = *(const float4*)(xr + 4);
  float ss = a.x * a.x + a.y * a.y + a.z * a.z + a.w * a.w
           + b.x * b.x + b.y * b.y + b.z * b.z + b.w * b.w;
#pragma unroll
  for (int m = 32; m; m >>= 1) ss += __shfl_xor(ss, m);
  const float scale = rsqrtf(ss * (1.0f / D_MODEL) + 1e-6f);
  const float4 wa = *(const float4*)(w + lane * 8);
  const float4 wb = *(const float4*)(w + lane * 8 + 4);
  short8 o;
  o[0] = f2bf(a.x * scale * wa.x);
  o[1] = f2bf(a.y * scale * wa.y);
  o[2] = f2bf(a.z * scale * wa.z);
  o[3] = f2bf(a.w * scale * wa.w);
  o[4] = f2bf(b.x * scale * wb.x);
  o[5] = f2bf(b.y * scale * wb.y);
  o[6] = f2bf(b.z * scale * wb.z);
  o[7] = f2bf(b.w * scale * wb.w);
  *(short8*)(outp + row * D_MODEL + lane * 8) = o;
}

// ---------- causal depthwise conv (K=17, dilation=1), bf16 in/out ----------
__global__ void dwconv_kernel(const short* __restrict__ hn, const float* __restrict__ wT,
                              short* __restrict__ hc) {
  const int tid = threadIdx.x;
  const int chunk = tid & 63;                       // 64 chunks of 8 channels
  const long row = (long)blockIdx.x * 4 + (tid >> 6);
  const int t = (int)(row & (TSEQ - 1));
  const int c0 = chunk * 8;
  float acc[8];
#pragma unroll
  for (int j = 0; j < 8; ++j) acc[j] = 0.f;
  const int kmin = (t >= 16) ? 0 : (16 - t);
  for (int k = kmin; k < 17; ++k) {
    const short8 h = *(const short8*)(hn + (row - 16 + k) * D_MODEL + c0);
    const float* wp = wT + k * D_MODEL + c0;
    const float4 w0 = *(const float4*)(wp);
    const float4 w1 = *(const float4*)(wp + 4);
    acc[0] += bf2f(h[0]) * w0.x;
    acc[1] += bf2f(h[1]) * w0.y;
    acc[2] += bf2f(h[2]) * w0.z;
    acc[3] += bf2f(h[3]) * w0.w;
    acc[4] += bf2f(h[4]) * w1.x;
    acc[5] += bf2f(h[5]) * w1.y;
    acc[6] += bf2f(h[6]) * w1.z;
    acc[7] += bf2f(h[7]) * w1.w;
  }
  short8 o;
#pragma unroll
  for (int j = 0; j < 8; ++j) o[j] = f2bf(acc[j]);
  *(short8*)(hc + row * D_MODEL + c0) = o;
}

// ---------- 128x128 GEMM, BK=32, dbuf LDS, counted vmcnt, 4 blocks/CU ----------
// C[M][N] = A[M][K](bf16) x Bt[N][K](bf16). 256 threads = 4 waves (2M x 2N),
// wave tile 64x64. BK=32. LDS = 2buf x (A 128x32 + B 128x32) x 2B = 32 KiB ->
// 4 blocks/CU = 16 waves/CU (4/SIMD) at ~90 VGPR. R9's cycle audit showed ~60%
// pure stall with 8 waves/CU (LDS 35%, matrix 28% busy): latency-bound, so the
// lever is wave count / independent blocks, schedule held constant from R9.
// Per K-tile (2 barriers, hazard-ledger-verified, same as R9 with 4 DMA/wave):
//   { stage(t+1)->buf^1 (4 DMA); vmcnt(4); BAR;      // stage(t) globally visible
//     8 asm ds_read(buf); lgkm0; 16 MFMA (setprio); BAR }
// Both-sides XOR chunk swizzle for the 64B row: stage pre-swizzle
// chunk=(lane&3)^((lane>>3)&3), read c=kchunk^(((lane&15)>>1)&3) -> <=2 lanes/bank.
// XCD-chunked block swizzle (grid % 8 == 0).
#define PHASE_BAR() __builtin_amdgcn_s_barrier()
#define LGKM0() { asm volatile("s_waitcnt lgkmcnt(0)" ::: "memory"); __builtin_amdgcn_sched_barrier(0); }
#define VMC4()  { asm volatile("s_waitcnt vmcnt(4)"   ::: "memory"); __builtin_amdgcn_sched_barrier(0); }
#define VMC0()  { asm volatile("s_waitcnt vmcnt(0)"   ::: "memory"); __builtin_amdgcn_sched_barrier(0); }
#define DSR1(dst, addr, imm) \
  asm volatile("ds_read_b128 %0, %1 offset:%2" : "=v"(dst) : "v"(addr), "i"(imm))

template <int EPI>
__global__ __launch_bounds__(256, 4)
void gemm128(const short* __restrict__ A, const short* __restrict__ Bt,
             const int K, const int N, const int nbn,
             const void* __restrict__ aux, void* __restrict__ outp) {
  __shared__ short Alds[2 * 128 * 32];   // [buf][row 128][k 32]
  __shared__ short Blds[2 * 128 * 32];
  const int tid = threadIdx.x;
  const int lane = tid & 63;
  const int w = tid >> 6;         // 0..3
  const int wm = w >> 1;          // 0..1  (M half)
  const int wn = w & 1;           // 0..1  (N half)

  // XCD-chunked swizzle; consecutive wids share the A-panel (nbn fastest)
  const int nwg = gridDim.x;
  const int cpx = nwg >> 3;
  const int bid = blockIdx.x;
  const int wid = (bid & 7) * cpx + (bid >> 3);
  const int brow = (wid / nbn) * 128;
  const int bcol = (wid % nbn) * 128;

  floatx4 acc[4][4];
#pragma unroll
  for (int i = 0; i < 4; ++i)
#pragma unroll
    for (int j = 0; j < 4; ++j) acc[i][j] = {0.f, 0.f, 0.f, 0.f};

  short8 af[4];   // A frags: 4 m-frags (K=32 slice)
  short8 bfr[4];  // B frags: 4 n-frags

  // staging: per wave 2 DMAs each for A and B; DMA = 16 rows x 64B (1 KiB linear).
  // lane -> row lane>>2, chunk (lane&3); source chunk pre-swizzled:
  const int chunkx = (lane & 3) ^ ((lane >> 3) & 3);   // (lane&3) ^ ((rowL>>1)&3)
  const short* gA = A + ((long)(brow + w * 32 + (lane >> 2))) * K + chunkx * 8;
  const short* gB = Bt + ((long)(bcol + w * 32 + (lane >> 2))) * K + chunkx * 8;
  const int kchunk = lane >> 4;   // 0..3 (k-offset kchunk*8 within BK=32)

  // asm ds_read addresses: frag byte = BUF*8192 + r*64 + c*16,
  //   r = half*64 + frag*16 + (lane&15), c = kchunk ^ (((lane&15)>>1)&3)
  const unsigned Abase = (unsigned)(uintptr_t)(__attribute__((address_space(3))) short*)Alds;
  const unsigned Bbase = (unsigned)(uintptr_t)(__attribute__((address_space(3))) short*)Blds;
  const unsigned lanelo = (unsigned)((lane & 15) * 64);
  const unsigned ct = (unsigned)((kchunk ^ (((lane & 15) >> 1) & 3)) * 16);
  const unsigned adrA = Abase + (unsigned)(wm * 4096) + lanelo + ct;
  const unsigned adrB = Bbase + (unsigned)(wn * 4096) + lanelo + ct;

#define STG(BUF, koff)                                                         \
  { _Pragma("unroll")                                                          \
    for (int j = 0; j < 2; ++j)                                                \
      gload_lds16(gA + (long)j * 16 * K + (koff),                              \
                  &Alds[((BUF) * 128 + w * 32 + j * 16) * 32]);                \
    _Pragma("unroll")                                                          \
    for (int j = 0; j < 2; ++j)                                                \
      gload_lds16(gB + (long)j * 16 * K + (koff),                              \
                  &Blds[((BUF) * 128 + w * 32 + j * 16) * 32]); }

#define READS(BUF) {                                                           \
    DSR1(af[0],  adrA, (BUF)*8192 + 0*1024);                                   \
    DSR1(af[1],  adrA, (BUF)*8192 + 1*1024);                                   \
    DSR1(af[2],  adrA, (BUF)*8192 + 2*1024);                                   \
    DSR1(af[3],  adrA, (BUF)*8192 + 3*1024);                                   \
    DSR1(bfr[0], adrB, (BUF)*8192 + 0*1024);                                   \
    DSR1(bfr[1], adrB, (BUF)*8192 + 1*1024);                                   \
    DSR1(bfr[2], adrB, (BUF)*8192 + 2*1024);                                   \
    DSR1(bfr[3], adrB, (BUF)*8192 + 3*1024); }

#define MMACL_ALL()                                                            \
  { __builtin_amdgcn_s_setprio(1);                                             \
    _Pragma("unroll")                                                          \
    for (int mi = 0; mi < 4; ++mi)                                             \
      _Pragma("unroll")                                                        \
      for (int ni = 0; ni < 4; ++ni)                                           \
        acc[mi][ni] = __builtin_amdgcn_mfma_f32_16x16x32_bf16(                 \
            af[mi], bfr[ni], acc[mi][ni], 0, 0, 0);                            \
    __builtin_amdgcn_s_setprio(0); }

  // TILE: DOST stages tile t+1 into BUF^1; W4 counted wait (steady), W0 tail drain.
#define TILE(BUF, DOST, W4, W0, LASTT, koff)                                   \
  {                                                                            \
    if (DOST) STG((BUF) ^ 1, koff);                                            \
    if (W4) VMC4();                                                            \
    if (W0) VMC0();                                                            \
    PHASE_BAR();                                                               \
    READS(BUF); LGKM0();                                                       \
    MMACL_ALL();                                                               \
    if (!LASTT) PHASE_BAR();                                                   \
  }

  // prologue: stage tile 0 into buf 0 (loop's vmcnt/BAR handles the drain)
  STG(0, 0);

  const int nkt = K >> 5;          // 16 or 64 at our call sites (even)
  for (int kt = 0; kt < nkt - 2; kt += 2) {
    TILE(0, 1, 1, 0, 0, (kt + 1) * 32);
    TILE(1, 1, 1, 0, 0, (kt + 2) * 32);
  }
  TILE(0, 1, 1, 0, 0, (nkt - 1) * 32);   // tile nkt-2: stage last tile
  TILE(1, 0, 0, 1, 1, 0);                // tile nkt-1: drain, compute, no end bar

#undef TILE
#undef MMACL_ALL
#undef READS
#undef STG

  // epilogue: C/D layout col=lane&15, row=(lane>>4)*4+j. 32-bit index math.
#pragma unroll
  for (int mi = 0; mi < 4; ++mi) {
    const int r0 = brow + wm * 64 + mi * 16 + (lane >> 4) * 4;
#pragma unroll
    for (int j = 0; j < 4; ++j) {
      const int rb = (r0 + j) * N;
      const int gcb = bcol + wn * 64 + (lane & 15);
#pragma unroll
      for (int ni = 0; ni < 4; ++ni) {
        const int idx = rb + gcb + ni * 16;
        const float v = acc[mi][ni][j];
        if (EPI == 0) {
          const float hcv = bf2f(((const short*)aux)[idx]);
          const float g = 1.f / (1.f + __expf(-v));
          ((short*)outp)[idx] = f2bf(g * hcv);
        } else if (EPI == 1) {
          ((float*)outp)[idx] = ((const float*)aux)[idx] + v;
        } else if (EPI == 2) {
          const float x3 = v * v * v;
          const float z = 0.7978845608028654f * (v + 0.044715f * x3);
          const float th = 1.f - 2.f / (__expf(2.f * z) + 1.f);   // tanh(z)
          ((short*)outp)[idx] = f2bf(0.5f * v * (1.f + th));
        } else {
          ((float*)outp)[idx] += v;
        }
      }
    }
  }
}

// ---------- launch ----------
extern "C" void kernel_launch(void* const* d_in, const int* in_sizes, int n_in,
                              void* d_out, int out_size, void* d_ws, size_t ws_size,
                              hipStream_t stream) {
  const float* x      = (const float*)d_in[0];
  const float* ln1_w  = (const float*)d_in[1];
  const float* gate_w = (const float*)d_in[2];   // [512][512]
  const float* conv_w = (const float*)d_in[3];   // [512][17]
  const float* proj_w = (const float*)d_in[4];   // [512][512]
  const float* ln2_w  = (const float*)d_in[5];
  const float* mlp_w1 = (const float*)d_in[6];   // [512][2048]
  const float* mlp_w2 = (const float*)d_in[7];   // [2048][512]
  float* out = (float*)d_out;
  char* ws = (char*)d_ws;

  // workspace layout (bytes), all offsets 256B-aligned
  short* hn      = (short*)(ws + 0);                       // 64 MiB  (also hn2 later)
  short* hc      = (short*)(ws + 67108864L);               // 64 MiB  (hc, then u in-place)
  short* mid     = (short*)(ws + 134217728L);              // 256 MiB
  short* gate_wt = (short*)(ws + 402653184L);              // 512 KiB [512][512]
  short* proj_wt = (short*)(ws + 403177472L);              // 512 KiB
  short* w1t     = (short*)(ws + 403701760L);              // 2 MiB   [2048][512]
  short* w2t     = (short*)(ws + 405798912L);              // 2 MiB   [512][2048]
  float* convwT  = (float*)(ws + 407896064L);              // 34 KiB  [17][512]

  const dim3 b256(256);

  // weights -> bf16 transposed (per-call; deterministic, ~5 MB)
  wt_transpose<<<dim3(8, 8),  b256, 0, stream>>>(gate_w, gate_wt, 512, 512);
  wt_transpose<<<dim3(8, 8),  b256, 0, stream>>>(proj_w, proj_wt, 512, 512);
  wt_transpose<<<dim3(8, 32), b256, 0, stream>>>(mlp_w1, w1t, 512, 2048);
  wt_transpose<<<dim3(32, 8), b256, 0, stream>>>(mlp_w2, w2t, 2048, 512);
  convw_transpose<<<34, b256, 0, stream>>>(conv_w, convwT);

  // 1) hn = rmsnorm(x, ln1_w)
  rmsnorm_kernel<<<NTOK / 4, b256, 0, stream>>>(x, ln1_w, hn);
  // 2) hc = causal_dwconv(hn)
  dwconv_kernel<<<NTOK / 4, b256, 0, stream>>>(hn, convwT, hc);
  // 3) u = sigmoid(hn @ gate_w) * hc   (in-place into hc)
  gemm128<0><<<512 * 4, b256, 0, stream>>>(hn, gate_wt, 512, 512, 4, hc, hc);
  // 4) x2 = x + u @ proj_w  -> d_out (f32)
  gemm128<1><<<512 * 4, b256, 0, stream>>>(hc, proj_wt, 512, 512, 4, x, out);
  // 5) hn2 = rmsnorm(x2, ln2_w)  (reuse hn buffer)
  rmsnorm_kernel<<<NTOK / 4, b256, 0, stream>>>(out, ln2_w, hn);
  // 6) mid = gelu(hn2 @ mlp_w1)
  gemm128<2><<<512 * 16, b256, 0, stream>>>(hn, w1t, 512, 2048, 16, nullptr, mid);
  // 7) out += mid @ mlp_w2
  gemm128<3><<<512 * 4, b256, 0, stream>>>(mid, w2t, 2048, 512, 4, nullptr, out);
}

// Round 11
// 694.805 us; speedup vs baseline: 1.0811x; 1.0811x over previous
//
#include <hip/hip_runtime.h>
#include <hip/hip_bf16.h>
#include <cstdint>
#include <cstddef>

// ---------- types ----------
typedef __attribute__((ext_vector_type(8))) short short8;   // bf16 x8 (4 VGPRs)
typedef __attribute__((ext_vector_type(4))) short short4v;  // bf16 x4
typedef __attribute__((ext_vector_type(4))) float floatx4;

#define D_MODEL 512
#define HDIM    2048
#define TSEQ    16384
#define NTOK    65536   // B*T = 4*16384

// ---------- helpers ----------
__device__ __forceinline__ float bf2f(short s) {
  union { unsigned u; float f; } v; v.u = ((unsigned)(unsigned short)s) << 16; return v.f;
}
__device__ __forceinline__ short f2bf(float f) {
  union { float fv; unsigned u; } v; v.fv = f;
  unsigned u = v.u;
  u += 0x7FFFu + ((u >> 16) & 1u);   // RNE
  return (short)(u >> 16);
}
__device__ __forceinline__ void gload_lds16(const void* g, void* l) {
  // width=16 async global->LDS; LDS dest = wave-uniform base + lane*16 (m104)
  __builtin_amdgcn_global_load_lds((const __attribute__((address_space(1))) void*)g,
                                   (__attribute__((address_space(3))) void*)l, 16, 0, 0);
}

// ---------- weight convert + transpose: W[K][N] f32 -> Wt[N][K] bf16 ----------
__global__ void wt_transpose(const float* __restrict__ W, short* __restrict__ Wt,
                             const int K, const int N) {
  __shared__ float t[64][65];
  const int tid = threadIdx.x;
  const long k0 = (long)blockIdx.x * 64;
  const long n0 = (long)blockIdx.y * 64;
  const int rr = tid >> 4;
  const int cc = (tid & 15) * 4;
#pragma unroll
  for (int i = 0; i < 4; ++i) {
    const int r = rr + i * 16;
    const float4 v = *(const float4*)(W + (k0 + r) * N + n0 + cc);
    t[r][cc + 0] = v.x; t[r][cc + 1] = v.y; t[r][cc + 2] = v.z; t[r][cc + 3] = v.w;
  }
  __syncthreads();
#pragma unroll
  for (int i = 0; i < 4; ++i) {
    const int n = rr + i * 16;
    short4v o;
    o[0] = f2bf(t[cc + 0][n]);
    o[1] = f2bf(t[cc + 1][n]);
    o[2] = f2bf(t[cc + 2][n]);
    o[3] = f2bf(t[cc + 3][n]);
    *(short4v*)(Wt + (n0 + n) * K + k0 + cc) = o;
  }
}

// conv_w [512][17] f32 -> wT [17][512] f32
__global__ void convw_transpose(const float* __restrict__ cw, float* __restrict__ wT) {
  const int idx = blockIdx.x * 256 + threadIdx.x;
  if (idx >= 17 * D_MODEL) return;
  const int k = idx / D_MODEL;
  const int c = idx % D_MODEL;
  wT[idx] = cw[c * 17 + k];
}

// ---------- RMSNorm: one wave per row, f32 in -> bf16 out ----------
__global__ void rmsnorm_kernel(const float* __restrict__ x, const float* __restrict__ w,
                               short* __restrict__ outp) {
  const int lane = threadIdx.x & 63;
  const long row = (long)blockIdx.x * 4 + (threadIdx.x >> 6);
  const float* xr = x + row * D_MODEL + lane * 8;
  const float4 a = *(const float4*)xr;
  const float4 b = *(const float4*)(xr + 4);
  float ss = a.x * a.x + a.y * a.y + a.z * a.z + a.w * a.w
           + b.x * b.x + b.y * b.y + b.z * b.z + b.w * b.w;
#pragma unroll
  for (int m = 32; m; m >>= 1) ss += __shfl_xor(ss, m);
  const float scale = rsqrtf(ss * (1.0f / D_MODEL) + 1e-6f);
  const float4 wa = *(const float4*)(w + lane * 8);
  const float4 wb = *(const float4*)(w + lane * 8 + 4);
  short8 o;
  o[0] = f2bf(a.x * scale * wa.x);
  o[1] = f2bf(a.y * scale * wa.y);
  o[2] = f2bf(a.z * scale * wa.z);
  o[3] = f2bf(a.w * scale * wa.w);
  o[4] = f2bf(b.x * scale * wb.x);
  o[5] = f2bf(b.y * scale * wb.y);
  o[6] = f2bf(b.z * scale * wb.z);
  o[7] = f2bf(b.w * scale * wb.w);
  *(short8*)(outp + row * D_MODEL + lane * 8) = o;
}

// ---------- causal depthwise conv (K=17, dilation=1), bf16 in/out ----------
__global__ void dwconv_kernel(const short* __restrict__ hn, const float* __restrict__ wT,
                              short* __restrict__ hc) {
  const int tid = threadIdx.x;
  const int chunk = tid & 63;                       // 64 chunks of 8 channels
  const long row = (long)blockIdx.x * 4 + (tid >> 6);
  const int t = (int)(row & (TSEQ - 1));
  const int c0 = chunk * 8;
  float acc[8];
#pragma unroll
  for (int j = 0; j < 8; ++j) acc[j] = 0.f;
  const int kmin = (t >= 16) ? 0 : (16 - t);
  for (int k = kmin; k < 17; ++k) {
    const short8 h = *(const short8*)(hn + (row - 16 + k) * D_MODEL + c0);
    const float* wp = wT + k * D_MODEL + c0;
    const float4 w0 = *(const float4*)(wp);
    const float4 w1 = *(const float4*)(wp + 4);
    acc[0] += bf2f(h[0]) * w0.x;
    acc[1] += bf2f(h[1]) * w0.y;
    acc[2] += bf2f(h[2]) * w0.z;
    acc[3] += bf2f(h[3]) * w0.w;
    acc[4] += bf2f(h[4]) * w1.x;
    acc[5] += bf2f(h[5]) * w1.y;
    acc[6] += bf2f(h[6]) * w1.z;
    acc[7] += bf2f(h[7]) * w1.w;
  }
  short8 o;
#pragma unroll
  for (int j = 0; j < 8; ++j) o[j] = f2bf(acc[j]);
  *(short8*)(hc + row * D_MODEL + c0) = o;
}

// ---------- 256x256 GEMM, 16x16x32 MFMA, 2-barrier self-paced tiles ----------
// IDENTICAL to the R6 best-kernel (692 us) except: NO s_setprio around the MFMA
// clusters. T5 is structure-conditional (m218b: +21-25% on 8-phase role-split;
// m190: NEGATIVE on lockstep) — this 2-barrier loop is m190-class, and prio-1
// MFMA bursts starve co-resident waves' ds_read/DMA issue, killing the
// inter-wave overlap that should hide lgkm/vmcnt waits.
// Per K-tile (waves SELF-PACED between barriers):
//   top:  stage A(t+1)->buf^1; 16 ds_read (A m0-3 + B n0-3); lgkm0; 32 MFMA
//   MID-BARRIER  (all waves' B(t)-reads complete -> B-half WAR safe)
//   stage B(t+2)->buf; 8 ds_read (A m4-7); lgkm0; 32 MFMA; vmcnt(4)
//   END-BARRIER  (A(t+1)/B(t+1) DMA complete for ALL waves; buf-swap WAR safe)
// Hazards: every stage lands >=1 barrier after its region's last read; every read
// >=1 vmcnt+barrier after its DMA issue. vmcnt(4)@end leaves exactly B(t+2) in flight.
// Frag reads are inline-asm ds_read_b128 (defeats conservative vmcnt(0) on LDS-DMA
// alias; rule #18 sched_barrier(0) after each manual waitcnt). Both-sides XOR chunk
// swizzle (16x16 pattern) -> 0 bank conflicts measured (R1-R4, R6).
#define PHASE_BAR() __builtin_amdgcn_s_barrier()
#define LGKM0() { asm volatile("s_waitcnt lgkmcnt(0)" ::: "memory"); __builtin_amdgcn_sched_barrier(0); }
#define VMC4()  { asm volatile("s_waitcnt vmcnt(4)"   ::: "memory"); __builtin_amdgcn_sched_barrier(0); }
#define VMC0()  { asm volatile("s_waitcnt vmcnt(0)"   ::: "memory"); __builtin_amdgcn_sched_barrier(0); }
// asm ds_read_b128: dst 4-VGPR tuple, addr VGPR, literal byte offset
#define DSR1(dst, addr, imm) \
  asm volatile("ds_read_b128 %0, %1 offset:%2" : "=v"(dst) : "v"(addr), "i"(imm))

template <int EPI>
__global__ __launch_bounds__(512, 2)
void gemm256(const short* __restrict__ A, const short* __restrict__ Bt,
             const int K, const int N, const int nbn,
             const void* __restrict__ aux, void* __restrict__ outp) {
  __shared__ short Alds[2 * 2 * 128 * 64];   // [buf][half][row 128][k 64]
  __shared__ short Blds[2 * 2 * 128 * 64];
  const int tid = threadIdx.x;
  const int lane = tid & 63;
  const int w = tid >> 6;
  const int wm = w >> 2;          // 0..1  (M half of block)
  const int wn = w & 3;           // 0..3  (N quarter of block)

  // XCD-chunked swizzle (all call sites have gridDim.x % 8 == 0)
  const int nwg = gridDim.x;
  const int cpx = nwg >> 3;
  const int bid = blockIdx.x;
  const int wid = (bid & 7) * cpx + (bid >> 3);
  const long brow = (long)(wid / nbn) * 256;
  const long bcol = (long)(wid % nbn) * 256;

  floatx4 acc[8][4];
#pragma unroll
  for (int i = 0; i < 8; ++i)
#pragma unroll
    for (int j = 0; j < 4; ++j) acc[i][j] = {0.f, 0.f, 0.f, 0.f};

  short8 af[4][2];   // A frags: 4 m-frags x 2 k-slices (rows mbase..mbase+3)
  short8 bfr[4][2];  // B frags: 4 n-frags x 2 k-slices (whole tile, held in regs)

  // staging addresses: pre-swizzled global chunk, linear LDS dest
  const int chunkx = (lane & 7) ^ (lane >> 3);
  const short* gA = A + (brow + w * 8 + (lane >> 3)) * (long)K + chunkx * 8;
  const short* gB = Bt + (bcol + w * 8 + (lane >> 3)) * (long)K + chunkx * 8;
  const int kchunk = lane >> 4;   // 0..3

  // ds_read base addresses (16x16 pattern, 0-conflict verified R1-R4):
  // frag byte = BUF*32768 + half*16384 + r*128 + c*16, r=(mbase+mi)*16+(lane&15),
  //   c=(ks*4+kchunk)^(lane&7)
  const unsigned Abase = (unsigned)(uintptr_t)(__attribute__((address_space(3))) short*)Alds;
  const unsigned Bbase = (unsigned)(uintptr_t)(__attribute__((address_space(3))) short*)Blds;
  const unsigned lanelo = (unsigned)((lane & 15) * 128);
  const unsigned c0t = (unsigned)(((0 + kchunk) ^ (lane & 7)) * 16);
  const unsigned c1t = (unsigned)(((4 + kchunk) ^ (lane & 7)) * 16);
  const unsigned adrA0 = Abase + (unsigned)(wm * 16384) + lanelo + c0t;
  const unsigned adrA1 = Abase + (unsigned)(wm * 16384) + lanelo + c1t;
  const unsigned adrB0 = Bbase + (unsigned)((wn >> 1) * 16384 + (wn & 1) * 8192) + lanelo + c0t;
  const unsigned adrB1 = Bbase + (unsigned)((wn >> 1) * 16384 + (wn & 1) * 8192) + lanelo + c1t;

#define STGA(half, BUF, koff)                                                  \
  { _Pragma("unroll")                                                          \
    for (int j = 0; j < 2; ++j)                                                \
      gload_lds16(gA + ((half) * 128 + j * 64) * (long)K + (koff),             \
                  &Alds[(((BUF) * 2 + (half)) * 128 + j * 64 + w * 8) * 64]); }
#define STGB(half, BUF, koff)                                                  \
  { _Pragma("unroll")                                                          \
    for (int j = 0; j < 2; ++j)                                                \
      gload_lds16(gB + ((half) * 128 + j * 64) * (long)K + (koff),             \
                  &Blds[(((BUF) * 2 + (half)) * 128 + j * 64 + w * 8) * 64]); }

#define LDA4(mbase, BUF) {                                                     \
    DSR1(af[0][0], adrA0, (BUF)*32768 + ((mbase)+0)*2048);                     \
    DSR1(af[0][1], adrA1, (BUF)*32768 + ((mbase)+0)*2048);                     \
    DSR1(af[1][0], adrA0, (BUF)*32768 + ((mbase)+1)*2048);                     \
    DSR1(af[1][1], adrA1, (BUF)*32768 + ((mbase)+1)*2048);                     \
    DSR1(af[2][0], adrA0, (BUF)*32768 + ((mbase)+2)*2048);                     \
    DSR1(af[2][1], adrA1, (BUF)*32768 + ((mbase)+2)*2048);                     \
    DSR1(af[3][0], adrA0, (BUF)*32768 + ((mbase)+3)*2048);                     \
    DSR1(af[3][1], adrA1, (BUF)*32768 + ((mbase)+3)*2048); }
#define LDB2(nbase, BUF) {                                                     \
    DSR1(bfr[(nbase)+0][0], adrB0, (BUF)*32768 + ((nbase)+0)*2048);            \
    DSR1(bfr[(nbase)+0][1], adrB1, (BUF)*32768 + ((nbase)+0)*2048);            \
    DSR1(bfr[(nbase)+1][0], adrB0, (BUF)*32768 + ((nbase)+1)*2048);            \
    DSR1(bfr[(nbase)+1][1], adrB1, (BUF)*32768 + ((nbase)+1)*2048); }

#define MMACL(mbase, nbase)                                                    \
  { _Pragma("unroll")                                                          \
    for (int mi = 0; mi < 4; ++mi)                                             \
      _Pragma("unroll")                                                        \
      for (int nn = 0; nn < 2; ++nn)                                           \
        _Pragma("unroll")                                                      \
        for (int ks = 0; ks < 2; ++ks)                                         \
          acc[(mbase) + mi][(nbase) + nn] = __builtin_amdgcn_mfma_f32_16x16x32_bf16( \
              af[mi][ks], bfr[(nbase) + nn][ks], acc[(mbase) + mi][(nbase) + nn], 0, 0, 0); }

  // TILE: DOSTA stages A(t+1)->BUF^1 at top; DOSTB stages B(t+2)->BUF at mid.
  // W4: vmcnt(4) before end-barrier (steady); W0: vmcnt(0) (tail drain).
  // LASTT: last tile -> skip barriers entirely.
#define TILE(BUF, DOSTA, DOSTB, W4, W0, LASTT, kA, kB)                         \
  {                                                                            \
    if (DOSTA) { STGA(0, (BUF) ^ 1, kA); STGA(1, (BUF) ^ 1, kA); }             \
    LDA4(0, BUF); LDB2(0, BUF); LDB2(2, BUF);                                  \
    LGKM0();                                                                   \
    MMACL(0, 0); MMACL(0, 2);                                                  \
    if (!LASTT) PHASE_BAR();      /* mid: all B(t)-reads done */               \
    if (DOSTB) { STGB(0, BUF, kB); STGB(1, BUF, kB); }                         \
    LDA4(4, BUF);                                                              \
    LGKM0();                                                                   \
    MMACL(4, 0); MMACL(4, 2);                                                  \
    if (W4) VMC4();                                                            \
    if (W0) VMC0();                                                            \
    if (!LASTT) PHASE_BAR();      /* end: DMA(t+1) visible; buf-swap safe */   \
  }

  // prologue: A(0), B(0), B(1); wait oldest 8 (A0,B0) done, leave B(1) in flight
  STGA(0, 0, 0); STGA(1, 0, 0);
  STGB(0, 0, 0); STGB(1, 0, 0);
  STGB(0, 1, 64); STGB(1, 1, 64);
  VMC4(); PHASE_BAR();

  const int nkt = K >> 6;          // 8 or 32 at our call sites (even, >= 8)
  int kA = 64, kB = 128;
  for (int t = 0; t < nkt - 2; t += 2) {
    TILE(0, 1, 1, 1, 0, 0, kA, kB); kA += 64; kB += 64;
    TILE(1, 1, 1, 1, 0, 0, kA, kB); kA += 64; kB += 64;
  }
  TILE(0, 1, 0, 0, 1, 0, kA, 0);   // tile nkt-2: stage A(nkt-1) only, full drain
  TILE(1, 0, 0, 0, 0, 1, 0, 0);    // tile nkt-1: pure compute, no barriers

#undef TILE
#undef MMACL
#undef LDA4
#undef LDB2
#undef STGA
#undef STGB

  // epilogue: C/D layout col=lane&15, row=(lane>>4)*4+j. 32-bit index math.
#pragma unroll
  for (int mi = 0; mi < 8; ++mi) {
    const int r0 = (int)brow + wm * 128 + mi * 16 + (lane >> 4) * 4;
#pragma unroll
    for (int j = 0; j < 4; ++j) {
      const int rb = (r0 + j) * N;
      const int gcb = (int)bcol + wn * 64 + (lane & 15);
#pragma unroll
      for (int ni = 0; ni < 4; ++ni) {
        const int idx = rb + gcb + ni * 16;
        const float v = acc[mi][ni][j];
        if (EPI == 0) {
          const float hcv = bf2f(((const short*)aux)[idx]);
          const float g = 1.f / (1.f + __expf(-v));
          ((short*)outp)[idx] = f2bf(g * hcv);
        } else if (EPI == 1) {
          ((float*)outp)[idx] = ((const float*)aux)[idx] + v;
        } else if (EPI == 2) {
          const float x3 = v * v * v;
          const float z = 0.7978845608028654f * (v + 0.044715f * x3);
          const float th = 1.f - 2.f / (__expf(2.f * z) + 1.f);   // tanh(z)
          ((short*)outp)[idx] = f2bf(0.5f * v * (1.f + th));
        } else {
          ((float*)outp)[idx] += v;
        }
      }
    }
  }
}

// ---------- launch ----------
extern "C" void kernel_launch(void* const* d_in, const int* in_sizes, int n_in,
                              void* d_out, int out_size, void* d_ws, size_t ws_size,
                              hipStream_t stream) {
  const float* x      = (const float*)d_in[0];
  const float* ln1_w  = (const float*)d_in[1];
  const float* gate_w = (const float*)d_in[2];   // [512][512]
  const float* conv_w = (const float*)d_in[3];   // [512][17]
  const float* proj_w = (const float*)d_in[4];   // [512][512]
  const float* ln2_w  = (const float*)d_in[5];
  const float* mlp_w1 = (const float*)d_in[6];   // [512][2048]
  const float* mlp_w2 = (const float*)d_in[7];   // [2048][512]
  float* out = (float*)d_out;
  char* ws = (char*)d_ws;

  // workspace layout (bytes), all offsets 256B-aligned
  short* hn      = (short*)(ws + 0);                       // 64 MiB  (also hn2 later)
  short* hc      = (short*)(ws + 67108864L);               // 64 MiB  (hc, then u in-place)
  short* mid     = (short*)(ws + 134217728L);              // 256 MiB
  short* gate_wt = (short*)(ws + 402653184L);              // 512 KiB [512][512]
  short* proj_wt = (short*)(ws + 403177472L);              // 512 KiB
  short* w1t     = (short*)(ws + 403701760L);              // 2 MiB   [2048][512]
  short* w2t     = (short*)(ws + 405798912L);              // 2 MiB   [512][2048]
  float* convwT  = (float*)(ws + 407896064L);              // 34 KiB  [17][512]

  const dim3 b256(256);
  const dim3 b512(512);

  // weights -> bf16 transposed (per-call; deterministic, ~5 MB)
  wt_transpose<<<dim3(8, 8),  b256, 0, stream>>>(gate_w, gate_wt, 512, 512);
  wt_transpose<<<dim3(8, 8),  b256, 0, stream>>>(proj_w, proj_wt, 512, 512);
  wt_transpose<<<dim3(8, 32), b256, 0, stream>>>(mlp_w1, w1t, 512, 2048);
  wt_transpose<<<dim3(32, 8), b256, 0, stream>>>(mlp_w2, w2t, 2048, 512);
  convw_transpose<<<34, b256, 0, stream>>>(conv_w, convwT);

  // 1) hn = rmsnorm(x, ln1_w)
  rmsnorm_kernel<<<NTOK / 4, b256, 0, stream>>>(x, ln1_w, hn);
  // 2) hc = causal_dwconv(hn)
  dwconv_kernel<<<NTOK / 4, b256, 0, stream>>>(hn, convwT, hc);
  // 3) u = sigmoid(hn @ gate_w) * hc   (in-place into hc)
  gemm256<0><<<256 * 2, b512, 0, stream>>>(hn, gate_wt, 512, 512, 2, hc, hc);
  // 4) x2 = x + u @ proj_w  -> d_out (f32)
  gemm256<1><<<256 * 2, b512, 0, stream>>>(hc, proj_wt, 512, 512, 2, x, out);
  // 5) hn2 = rmsnorm(x2, ln2_w)  (reuse hn buffer)
  rmsnorm_kernel<<<NTOK / 4, b256, 0, stream>>>(out, ln2_w, hn);
  // 6) mid = gelu(hn2 @ mlp_w1)
  gemm256<2><<<256 * 8, b512, 0, stream>>>(hn, w1t, 512, 2048, 8, nullptr, mid);
  // 7) out += mid @ mlp_w2
  gemm256<3><<<256 * 2, b512, 0, stream>>>(mid, w2t, 2048, 512, 2, nullptr, out);
}